// Round 4
// baseline (243.669 us; speedup 1.0000x reference)
//
#include <hip/hip_runtime.h>
#include <hip/hip_bf16.h>
#include <stdint.h>

#define D_EMB 128
#define D_NLP 768
#define BM 64
#define BK 64
#define NKC (D_NLP / BK)   // 12 k-chunks

typedef __attribute__((ext_vector_type(8))) short bf16x8;
typedef __attribute__((ext_vector_type(4))) float f32x4;
typedef __attribute__((ext_vector_type(8))) unsigned short u16x8;

__device__ __forceinline__ unsigned short f2bf(float f) {
  unsigned u = __builtin_bit_cast(unsigned, f);
  u += 0x7fffu + ((u >> 16) & 1u);   // RTNE (NaN-free inputs)
  return (unsigned short)(u >> 16);
}

// ---- kernel W: w0 (128x768 f32) -> bf16 row-major (no swizzle; B is consumed
// straight from L2 now). Also initializes mn.
__global__ void kw(const float* __restrict__ w0, unsigned short* __restrict__ w0b,
                   int* __restrict__ mn) {
  int t = blockIdx.x * 256 + threadIdx.x;       // 12288 threads total
  if (t == 0) mn[0] = 0x7fffffff;
  if (t >= (D_EMB * D_NLP) / 8) return;
  const float4* src = (const float4*)(w0 + (size_t)t * 8);
  float4 v0 = src[0], v1 = src[1];
  u16x8 o;
  o[0] = f2bf(v0.x); o[1] = f2bf(v0.y); o[2] = f2bf(v0.z); o[3] = f2bf(v0.w);
  o[4] = f2bf(v1.x); o[5] = f2bf(v1.y); o[6] = f2bf(v1.z); o[7] = f2bf(v1.w);
  *(u16x8*)(w0b + (size_t)t * 8) = o;
}

// ---- kernel M: mn = min_e max(ei[0][e], ei[1][e])
__global__ void km(const int* __restrict__ ei, int E, int* __restrict__ mn) {
  int t = blockIdx.x * blockDim.x + threadIdx.x;
  int stride = gridDim.x * blockDim.x;
  int m = 0x7fffffff;
  for (int e = t; e < E; e += stride) {
    int a = ei[e], b = ei[E + e];
    int q = a > b ? a : b;
    m = q < m ? q : m;
  }
  #pragma unroll
  for (int off = 32; off; off >>= 1) {
    int o = __shfl_xor(m, off);
    m = o < m ? o : m;
  }
  if ((threadIdx.x & 63) == 0) atomicMin(mn, m);
}

// ---- kernel C (fused, barrier-free): per 64-node tile:
//   sv[n] = sum_d prelu(z0[n].w0[d,:]) * w1c[d]
//   ta[n] = z[n].w1a, tb[n] = z[n].w1b
// NO LDS, NO __syncthreads: B fragments are read per-MFMA from L2-resident
// w0b (192 KB); A is prefetched 2 k-chunks deep into registers. Every wave
// free-runs with only compiler-counted waitcnts -> no global drain points.
__global__ __launch_bounds__(256) void kc(
    const float* __restrict__ z0, const float* __restrict__ z,
    const unsigned short* __restrict__ w0b, const float* __restrict__ w1,
    const float* __restrict__ prelu_a, float* __restrict__ sv,
    float* __restrict__ ta, float* __restrict__ tb, int N) {
  const int tid = threadIdx.x;
  const int lane = tid & 63;
  const int wave = tid >> 6;
  const int kg = lane >> 4;        // k-group: 8 elems each
  const int col = lane & 15;       // A row-within-16 / B col-within-16
  const int myrow = blockIdx.x * BM + wave * 16 + col;
  const int arow_g = min(myrow, N - 1);
  const float* aBase = z0 + (size_t)arow_g * D_NLP + kg * 8;
  const unsigned short* bBase = w0b + (size_t)col * D_NLP + kg * 8;

  f32x4 acc[8];
  #pragma unroll
  for (int c = 0; c < 8; ++c) acc[c] = (f32x4){0.f, 0.f, 0.f, 0.f};

  float4 fa[3][4];   // 2-deep A prefetch, statically indexed (loop fully unrolled)

  auto loadA = [&](float4* f, int t) {
    const float4* p0 = (const float4*)(aBase + t * BK);        // ks=0: k = ks*32+kg*8+j
    const float4* p1 = (const float4*)(aBase + t * BK + 32);   // ks=1
    f[0] = p0[0]; f[1] = p0[1]; f[2] = p1[0]; f[3] = p1[1];
  };

  loadA(fa[0], 0);
  loadA(fa[1], 1);

  #pragma unroll
  for (int t = 0; t < NKC; ++t) {
    if (t + 2 < NKC) loadA(fa[(t + 2) % 3], t + 2);
    const float4* f = fa[t % 3];
    u16x8 v;
    v[0] = f2bf(f[0].x); v[1] = f2bf(f[0].y); v[2] = f2bf(f[0].z); v[3] = f2bf(f[0].w);
    v[4] = f2bf(f[1].x); v[5] = f2bf(f[1].y); v[6] = f2bf(f[1].z); v[7] = f2bf(f[1].w);
    bf16x8 af0 = __builtin_bit_cast(bf16x8, v);
    v[0] = f2bf(f[2].x); v[1] = f2bf(f[2].y); v[2] = f2bf(f[2].z); v[3] = f2bf(f[2].w);
    v[4] = f2bf(f[3].x); v[5] = f2bf(f[3].y); v[6] = f2bf(f[3].z); v[7] = f2bf(f[3].w);
    bf16x8 af1 = __builtin_bit_cast(bf16x8, v);
    #pragma unroll
    for (int c = 0; c < 8; ++c) {
      const unsigned short* bp = bBase + (size_t)c * 16 * D_NLP + t * BK;
      bf16x8 b0 = *(const bf16x8*)bp;           // k = kg*8 + [0,8)
      bf16x8 b1 = *(const bf16x8*)(bp + 32);    // k = 32 + kg*8 + [0,8)
      acc[c] = __builtin_amdgcn_mfma_f32_16x16x32_bf16(af0, b0, acc[c], 0, 0, 0);
      acc[c] = __builtin_amdgcn_mfma_f32_16x16x32_bf16(af1, b1, acc[c], 0, 0, 0);
    }
  }

  // epilogue 1: prelu + * w1c[col-block], reduce the 16 cols held per lane-group
  float ap = prelu_a[0];
  float ssum[4] = {0.f, 0.f, 0.f, 0.f};
  #pragma unroll
  for (int c = 0; c < 8; ++c) {
    float wc = w1[2 * D_EMB + c * 16 + col];
    #pragma unroll
    for (int i = 0; i < 4; ++i) {
      float h = acc[c][i];
      float x = h >= 0.f ? h : ap * h;
      ssum[i] += x * wc;
    }
  }
  #pragma unroll
  for (int off = 1; off < 16; off <<= 1) {
    #pragma unroll
    for (int i = 0; i < 4; ++i) ssum[i] += __shfl_xor(ssum[i], off);
  }
  if (col == 0) {
    int rbase = blockIdx.x * BM + wave * 16 + kg * 4;   // D row = (lane>>4)*4 + i
    #pragma unroll
    for (int i = 0; i < 4; ++i) {
      int r = rbase + i;
      if (r < N) sv[r] = ssum[i];
    }
  }

  // epilogue 2 (fused kt): ta/tb for this block's 64 rows; row = col, kg splits D_EMB.
  {
    const float* zp = z + (size_t)arow_g * D_EMB + kg * 32;
    const float4* wa4 = (const float4*)(w1 + kg * 32);
    const float4* wb4 = (const float4*)(w1 + D_EMB + kg * 32);
    float pa = 0.f, pb = 0.f;
    #pragma unroll
    for (int i = 0; i < 8; ++i) {
      float4 zv = ((const float4*)zp)[i];
      float4 wa = wa4[i];
      float4 wb = wb4[i];
      pa += zv.x * wa.x + zv.y * wa.y + zv.z * wa.z + zv.w * wa.w;
      pb += zv.x * wb.x + zv.y * wb.y + zv.z * wb.z + zv.w * wb.w;
    }
    pa += __shfl_xor(pa, 16); pa += __shfl_xor(pa, 32);
    pb += __shfl_xor(pb, 16); pb += __shfl_xor(pb, 32);
    if (kg == 0 && myrow < N) { ta[myrow] = pa; tb[myrow] = pb; }
  }
}

// ---- kernel D: per-edge gather + add
__global__ void kd(const int* __restrict__ ei, const int* __restrict__ mn,
                   const float* __restrict__ ta, const float* __restrict__ tb,
                   const float* __restrict__ sv, const float* __restrict__ b1,
                   float* __restrict__ out, int E) {
  int e = blockIdx.x * blockDim.x + threadIdx.x;
  if (e >= E) return;
  int i0 = ei[e], i1 = ei[E + e];
  int q = (i0 > i1 ? i0 : i1) - mn[0];
  out[e] = ta[i0] + tb[i1] + sv[q] + b1[0];
}

extern "C" void kernel_launch(void* const* d_in, const int* in_sizes, int n_in,
                              void* d_out, int out_size, void* d_ws, size_t ws_size,
                              hipStream_t stream) {
  const float* z  = (const float*)d_in[0];
  const float* z0 = (const float*)d_in[1];
  const int*   ei = (const int*)d_in[2];
  const float* w0 = (const float*)d_in[3];
  const float* pa = (const float*)d_in[4];
  const float* w1 = (const float*)d_in[5];
  const float* b1 = (const float*)d_in[6];
  float* out = (float*)d_out;
  const int N = in_sizes[0] / D_EMB;
  const int E = in_sizes[2] / 2;

  // workspace layout (~1.4 MB):
  // [0,4) mn | [256, 256+196608) w0 bf16 row-major | ta[N], tb[N], sv[N] f32
  char* ws = (char*)d_ws;
  int* mn = (int*)ws;
  unsigned short* w0b = (unsigned short*)(ws + 256);
  float* ta = (float*)(ws + 256 + 196608);
  float* tb = ta + N;
  float* sv = tb + N;

  kw<<<(D_EMB * D_NLP / 8 + 255) / 256, 256, 0, stream>>>(w0, w0b, mn);
  km<<<256, 256, 0, stream>>>(ei, E, mn);
  kc<<<(N + BM - 1) / BM, 256, 0, stream>>>(z0, z, w0b, w1, pa, sv, ta, tb, N);
  kd<<<(E + 255) / 256, 256, 0, stream>>>(ei, mn, ta, tb, sv, b1, out, E);
}

// Round 5
// 124.786 us; speedup vs baseline: 1.9527x; 1.9527x over previous
//
#include <hip/hip_runtime.h>
#include <hip/hip_bf16.h>
#include <stdint.h>

#define D_EMB 128
#define D_NLP 768
#define BM 64
#define BK 64
#define NKC (D_NLP / BK)   // 12 k-chunks

typedef __attribute__((ext_vector_type(8))) short bf16x8;
typedef __attribute__((ext_vector_type(4))) float f32x4;
typedef __attribute__((ext_vector_type(8))) unsigned short u16x8;

__device__ __forceinline__ unsigned short f2bf(float f) {
  unsigned u = __builtin_bit_cast(unsigned, f);
  u += 0x7fffu + ((u >> 16) & 1u);   // RTNE (NaN-free inputs)
  return (unsigned short)(u >> 16);
}

// ---- kernel W: w0 (128x768 f32) -> bf16, pre-swizzled per k-chunk so a linear
// lane-order copy (global_load_lds) yields the XOR-swizzled LDS layout.
// Also initializes mn.
__global__ void kw(const float* __restrict__ w0, unsigned short* __restrict__ w0s,
                   int* __restrict__ mn) {
  if (blockIdx.x == 0 && threadIdx.x == 0) mn[0] = 0x7fffffff;
  int t = blockIdx.x * 256 + threadIdx.x;       // 12288 threads total
  if (t >= (D_EMB * D_NLP) / 8) return;
  int u = t & 7, row = (t >> 3) & 127, kc = t >> 10;
  const float4* src = (const float4*)(w0 + (size_t)row * D_NLP + kc * BK + ((u ^ (row & 7)) * 8));
  float4 v0 = src[0], v1 = src[1];
  u16x8 o;
  o[0] = f2bf(v0.x); o[1] = f2bf(v0.y); o[2] = f2bf(v0.z); o[3] = f2bf(v0.w);
  o[4] = f2bf(v1.x); o[5] = f2bf(v1.y); o[6] = f2bf(v1.z); o[7] = f2bf(v1.w);
  *(u16x8*)(w0s + (size_t)t * 8) = o;
}

// ---- kernel M: mn = min_e max(ei[0][e], ei[1][e])
__global__ void km(const int* __restrict__ ei, int E, int* __restrict__ mn) {
  int t = blockIdx.x * blockDim.x + threadIdx.x;
  int stride = gridDim.x * blockDim.x;
  int m = 0x7fffffff;
  for (int e = t; e < E; e += stride) {
    int a = ei[e], b = ei[E + e];
    int q = a > b ? a : b;
    m = q < m ? q : m;
  }
  #pragma unroll
  for (int off = 32; off; off >>= 1) {
    int o = __shfl_xor(m, off);
    m = o < m ? o : m;
  }
  if ((threadIdx.x & 63) == 0) atomicMin(mn, m);
}

// ---- kernel C (fused, counted-vmcnt pipeline): per 64-node tile:
//   sv[n] = sum_d prelu(z0[n].w0[d,:]) * w1c[d]
//   ta[n] = z[n].w1a, tb[n] = z[n].w1b
// A: global->reg, prefetched 2 chunks deep (fa ring of 3).
// B: pre-swizzled bf16 w0s staged via global_load_lds into a 3-buffer LDS ring.
// Main loop: s_waitcnt vmcnt(8) (the next chunk's 8 loads stay in flight
// across the barrier) -> s_barrier -> issue chunk t+2 -> compute chunk t.
// vmcnt never drains to 0 until the last iteration (T3+T4).
__global__ __launch_bounds__(256) void kc(
    const float* __restrict__ z0, const float* __restrict__ z,
    const unsigned short* __restrict__ w0s, const float* __restrict__ w1,
    const float* __restrict__ prelu_a, float* __restrict__ sv,
    float* __restrict__ ta, float* __restrict__ tb, int N) {
  __shared__ unsigned short Bb[3][D_EMB * BK];   // 16KB x3 = 48KB

  const int tid = threadIdx.x;
  const int lane = tid & 63;
  const int wave = tid >> 6;
  const int kg = lane >> 4;        // k-group: 8 elems each
  const int col = lane & 15;
  const int myrow = blockIdx.x * BM + wave * 16 + col;
  const int arow_g = min(myrow, N - 1);
  const float* aBase = z0 + (size_t)arow_g * D_NLP + kg * 8;

  f32x4 acc[8];
  #pragma unroll
  for (int c = 0; c < 8; ++c) acc[c] = (f32x4){0.f, 0.f, 0.f, 0.f};

  float4 fa[3][4];   // 2-deep A prefetch ring, statically indexed (unrolled loop)

  auto loadA = [&](int slot, int t) {
    const float4* p0 = (const float4*)(aBase + t * BK);        // ks=0: k = kg*8+[0,8)
    const float4* p1 = (const float4*)(aBase + t * BK + 32);   // ks=1
    fa[slot][0] = p0[0]; fa[slot][1] = p0[1];
    fa[slot][2] = p1[0]; fa[slot][3] = p1[1];
  };

  auto stageB = [&](int t, int buf) {
    const unsigned short* g = w0s + (size_t)t * (D_EMB * BK) + (size_t)tid * 8;
    #pragma unroll
    for (int p = 0; p < 4; ++p) {
      __builtin_amdgcn_global_load_lds(
          (const __attribute__((address_space(1))) void*)(g + p * 256 * 8),
          (__attribute__((address_space(3))) void*)&Bb[buf][(wave * 64 + p * 256) * 8],
          16, 0, 0);
    }
  };

  // prologue: chunks 0 and 1 in flight (16 vmem ops)
  loadA(0, 0); stageB(0, 0);
  loadA(1, 1); stageB(1, 1);

  #pragma unroll
  for (int t = 0; t < NKC; ++t) {
    // wait until only the NEXT chunk's 8 loads remain outstanding
    if (t < NKC - 1) asm volatile("s_waitcnt vmcnt(8)" ::: "memory");
    else             asm volatile("s_waitcnt vmcnt(0)" ::: "memory");
    __builtin_amdgcn_s_barrier();         // all waves' chunk-t stage landed
    if (t + 2 < NKC) {                    // issue chunk t+2 into ring slot
      loadA((t + 2) % 3, t + 2);
      stageB(t + 2, (t + 2) % 3);
    }
    __builtin_amdgcn_sched_barrier(0);    // pin issue block above compute

    const float4* f = fa[t % 3];
    u16x8 v;
    v[0] = f2bf(f[0].x); v[1] = f2bf(f[0].y); v[2] = f2bf(f[0].z); v[3] = f2bf(f[0].w);
    v[4] = f2bf(f[1].x); v[5] = f2bf(f[1].y); v[6] = f2bf(f[1].z); v[7] = f2bf(f[1].w);
    bf16x8 af0 = __builtin_bit_cast(bf16x8, v);
    v[0] = f2bf(f[2].x); v[1] = f2bf(f[2].y); v[2] = f2bf(f[2].z); v[3] = f2bf(f[2].w);
    v[4] = f2bf(f[3].x); v[5] = f2bf(f[3].y); v[6] = f2bf(f[3].z); v[7] = f2bf(f[3].w);
    bf16x8 af1 = __builtin_bit_cast(bf16x8, v);

    const unsigned short* Bbuf = Bb[t % 3];
    #pragma unroll
    for (int ks = 0; ks < 2; ++ks) {
      bf16x8 af = ks == 0 ? af0 : af1;
      #pragma unroll
      for (int c = 0; c < 8; ++c) {
        int brow = c * 16 + col;
        bf16x8 bfr = *(const bf16x8*)&Bbuf[(brow * 8 + ((ks * 4 + kg) ^ (brow & 7))) * 8];
        acc[c] = __builtin_amdgcn_mfma_f32_16x16x32_bf16(af, bfr, acc[c], 0, 0, 0);
      }
    }
  }

  // epilogue 1: prelu + * w1c[col-block], reduce the 16 cols held per lane-group
  float ap = prelu_a[0];
  float ssum[4] = {0.f, 0.f, 0.f, 0.f};
  #pragma unroll
  for (int c = 0; c < 8; ++c) {
    float wc = w1[2 * D_EMB + c * 16 + col];
    #pragma unroll
    for (int i = 0; i < 4; ++i) {
      float h = acc[c][i];
      float x = h >= 0.f ? h : ap * h;
      ssum[i] += x * wc;
    }
  }
  #pragma unroll
  for (int off = 1; off < 16; off <<= 1) {
    #pragma unroll
    for (int i = 0; i < 4; ++i) ssum[i] += __shfl_xor(ssum[i], off);
  }
  if (col == 0) {
    int rbase = blockIdx.x * BM + wave * 16 + kg * 4;   // D row = (lane>>4)*4 + i
    #pragma unroll
    for (int i = 0; i < 4; ++i) {
      int r = rbase + i;
      if (r < N) sv[r] = ssum[i];
    }
  }

  // epilogue 2 (fused kt): ta/tb for this block's 64 rows; row = col, kg splits D_EMB.
  {
    const float* zp = z + (size_t)arow_g * D_EMB + kg * 32;
    const float4* wa4 = (const float4*)(w1 + kg * 32);
    const float4* wb4 = (const float4*)(w1 + D_EMB + kg * 32);
    float pa = 0.f, pb = 0.f;
    #pragma unroll
    for (int i = 0; i < 8; ++i) {
      float4 zv = ((const float4*)zp)[i];
      float4 wa = wa4[i];
      float4 wb = wb4[i];
      pa += zv.x * wa.x + zv.y * wa.y + zv.z * wa.z + zv.w * wa.w;
      pb += zv.x * wb.x + zv.y * wb.y + zv.z * wb.z + zv.w * wb.w;
    }
    pa += __shfl_xor(pa, 16); pa += __shfl_xor(pa, 32);
    pb += __shfl_xor(pb, 16); pb += __shfl_xor(pb, 32);
    if (kg == 0 && myrow < N) { ta[myrow] = pa; tb[myrow] = pb; }
  }
}

// ---- kernel D: per-edge gather + add
__global__ void kd(const int* __restrict__ ei, const int* __restrict__ mn,
                   const float* __restrict__ ta, const float* __restrict__ tb,
                   const float* __restrict__ sv, const float* __restrict__ b1,
                   float* __restrict__ out, int E) {
  int e = blockIdx.x * blockDim.x + threadIdx.x;
  if (e >= E) return;
  int i0 = ei[e], i1 = ei[E + e];
  int q = (i0 > i1 ? i0 : i1) - mn[0];
  out[e] = ta[i0] + tb[i1] + sv[q] + b1[0];
}

extern "C" void kernel_launch(void* const* d_in, const int* in_sizes, int n_in,
                              void* d_out, int out_size, void* d_ws, size_t ws_size,
                              hipStream_t stream) {
  const float* z  = (const float*)d_in[0];
  const float* z0 = (const float*)d_in[1];
  const int*   ei = (const int*)d_in[2];
  const float* w0 = (const float*)d_in[3];
  const float* pa = (const float*)d_in[4];
  const float* w1 = (const float*)d_in[5];
  const float* b1 = (const float*)d_in[6];
  float* out = (float*)d_out;
  const int N = in_sizes[0] / D_EMB;
  const int E = in_sizes[2] / 2;

  // workspace layout (~1.4 MB):
  // [0,4) mn | [256, 256+196608) w0 bf16 pre-swizzled | ta[N], tb[N], sv[N] f32
  char* ws = (char*)d_ws;
  int* mn = (int*)ws;
  unsigned short* w0s = (unsigned short*)(ws + 256);
  float* ta = (float*)(ws + 256 + 196608);
  float* tb = ta + N;
  float* sv = tb + N;

  kw<<<(D_EMB * D_NLP / 8 + 255) / 256, 256, 0, stream>>>(w0, w0s, mn);
  km<<<256, 256, 0, stream>>>(ei, E, mn);
  kc<<<(N + BM - 1) / BM, 256, 0, stream>>>(z0, z, w0s, w1, pa, sv, ta, tb, N);
  kd<<<(E + 255) / 256, 256, 0, stream>>>(ei, mn, ta, tb, sv, b1, out, E);
}